// Round 5
// baseline (251.500 us; speedup 1.0000x reference)
//
#include <hip/hip_runtime.h>

// Box3dAttention: B=2, LQ=4096, d=256, heads=8, head_dim=32, 5x5=25 points,
// feature map 188x188 (LV=35344).
//
// Round 13 == round 12 resubmitted verbatim (round-12 bench failed on
// GPUAcquisitionTimeout; kernel never ran).
//
// Round 12 = round 11 with the MFMA GEMMs REWRITTEN as no-LDS direct-register
// kernels:
//  - K=256 means each lane's MFMA fragment is a contiguous 16B (bf16) or 32B
//    (fp32) run of one row -> load global->VGPR directly with compile-time
//    offset immediates. No LDS tiles, no ds_write/ds_read, NO BARRIERS.
//  - K1: BM=64 x BN=256 (one block reads its A-tile once; no n-split dup),
//    4 waves (2x2), wave tile 32x128, fp32 A loads + in-reg f2bf pack.
//  - K4: BM=64 x BN=128, direct bf16 A loads, grid (128,2)=256 blocks.
//  - Rationale: rounds 10/11 proved the LDS-barrier structure pinned K1 at
//    ~44us (2 blocks/CU, 8 waves/CU, VGPR=92: compiler never held prefetch
//    across MFMA). Occupancy now VGPR-bound, no sync convoys.
//  - MFMA sequence (kc->kb->ti->tj) and f2bf inputs identical -> bitwise-same
//    outputs vs rounds 8-11.
//
// Pipeline:
//  K0 convert    : W_value/W_out -> bf16, [W_attn;W_box] -> fp32 pad, bias pad
//  K1 gemm_direct<1,1,64,256>: value fp32 @ wvbf^T + b_value -> Vout bf16
//                    head-major [b*8+h][LV][32]
//  K2 gemm_nt    : fp32 VALU logits = query @ [W_attn;W_box]^T + b (box accuracy)
//  K3 decode_sample: block=(slice s=b*8+h, 8 q); XCD-temporal remap
//  K4 gemm_direct<0,0,64,128>: ohbf @ wobf^T + b_out -> out fp32

typedef float floatx4 __attribute__((ext_vector_type(4)));
typedef short shortx8 __attribute__((ext_vector_type(8)));

static __device__ __forceinline__ unsigned short f2bf(float x) {
    unsigned int u = __float_as_uint(x);
    return (unsigned short)((u + 0x7fffu + ((u >> 16) & 1u)) >> 16);
}
static __device__ __forceinline__ unsigned int pack2(float a, float b) {
    return (unsigned int)f2bf(a) | ((unsigned int)f2bf(b) << 16);
}

// ---------------- K0: weight/bias conversions only ----------------
// grid = 16 (W_value) + 16 (Wab fp32 pad) + 16 (W_out) + 1 (bias) = 49
__global__ __launch_bounds__(256) void convert_kernel(
    const float* __restrict__ W_value, unsigned short* __restrict__ wvbf,
    const float* __restrict__ W_attn, const float* __restrict__ W_box,
    float* __restrict__ Wab,
    const float* __restrict__ W_out, unsigned short* __restrict__ wobf,
    const float* __restrict__ b_attn, const float* __restrict__ b_box,
    float* __restrict__ bab)
{
    const int blk = blockIdx.x, tid = threadIdx.x;
    if (blk < 16) {
        int base = blk * 1024 + tid;
#pragma unroll
        for (int k = 0; k < 4; ++k) {
            int j = base + k * 256;
            float4 f = ((const float4*)W_value)[j];
            ((uint2*)wvbf)[j] = make_uint2(pack2(f.x, f.y), pack2(f.z, f.w));
        }
    } else if (blk < 32) {
        int base = (blk - 16) * 1024 + tid;
#pragma unroll
        for (int k = 0; k < 4; ++k) {
            int j = base + k * 256;
            int row = j >> 6, col = (j & 63) * 4;
            float4 f;
            if (row < 200)      f = *(const float4*)(W_attn + (size_t)row * 256 + col);
            else if (row < 240) f = *(const float4*)(W_box + (size_t)(row - 200) * 256 + col);
            else                f = make_float4(0.f, 0.f, 0.f, 0.f);
            ((float4*)Wab)[j] = f;
        }
    } else if (blk < 48) {
        int base = (blk - 32) * 1024 + tid;
#pragma unroll
        for (int k = 0; k < 4; ++k) {
            int j = base + k * 256;
            float4 f = ((const float4*)W_out)[j];
            ((uint2*)wobf)[j] = make_uint2(pack2(f.x, f.y), pack2(f.z, f.w));
        }
    } else {
        bab[tid] = tid < 200 ? b_attn[tid] : (tid < 240 ? b_box[tid - 200] : 0.f);
    }
}

// ---------------- no-LDS direct-register bf16 MFMA GEMM ----------------
// C = A(M x 256) @ Bw(256 x 256 bf16)^T + bias
// 4 waves (2x2), wave tile (BM/2) x (BN/2); TI=BM/32 m-frags, TJ=BN/32 n-frags.
// Each lane loads its fragments straight from global (16B bf16 / 2x16B fp32,
// compile-time offset immediates within the 1KB/512B row). Zero LDS, zero
// barriers; occupancy is VGPR-bound; latency hidden by TLP + straight-line
// load/MFMA interleave.
// AFP32=1: A fp32, in-register f2bf pack (bitwise == old LDS path).
// mfma(bfr, af, acc) => D^T layout: col(lane&15)=m, row(lq*4+r)=n.
// OUTMODE 0: C fp32 row-major [M][256]; OUTMODE 1: C bf16 head-major [b*8+h][LV][32]
template <int OUTMODE, int AFP32, int BM, int BN>
__global__ __launch_bounds__(256) void gemm_direct(
    const void* __restrict__ Av,
    const unsigned short* __restrict__ Bw,
    const float* __restrict__ bias,
    void* __restrict__ Cv, int M, int LV)
{
    constexpr int TI = BM / 32;
    constexpr int TJ = BN / 32;
    const int tid = threadIdx.x;
    const int wv = tid >> 6, lane = tid & 63;
    const int lr = lane & 15, lq = lane >> 4;
    const int m0 = blockIdx.x * BM, n0 = blockIdx.y * BN;
    const int wm = wv & 1, wn = wv >> 1;

    floatx4 acc[TI][TJ];
#pragma unroll
    for (int i = 0; i < TI; ++i)
#pragma unroll
        for (int j = 0; j < TJ; ++j) acc[i][j] = (floatx4){0.f, 0.f, 0.f, 0.f};

    // per-lane row base pointers (k-offset folded into the load immediate)
    const float* apf[TI];
    const unsigned short* apb[TI];
#pragma unroll
    for (int t = 0; t < TI; ++t) {
        int ra = m0 + wm * (BM / 2) + t * 16 + lr; ra = ra < M ? ra : M - 1;
        if constexpr (AFP32) apf[t] = (const float*)Av + (size_t)ra * 256 + lq * 8;
        else                 apb[t] = (const unsigned short*)Av + (size_t)ra * 256 + lq * 8;
    }
    const unsigned short* bp[TJ];
#pragma unroll
    for (int t = 0; t < TJ; ++t) {
        int rb = n0 + wn * (BN / 2) + t * 16 + lr;
        bp[t] = Bw + (size_t)rb * 256 + lq * 8;
    }

#pragma unroll
    for (int kc = 0; kc < 4; ++kc) {
#pragma unroll
        for (int kb = 0; kb < 2; ++kb) {
            const int ko = kc * 64 + kb * 32;
            shortx8 af[TI], bfr[TJ];
#pragma unroll
            for (int t = 0; t < TJ; ++t)
                bfr[t] = *(const shortx8*)(bp[t] + ko);
#pragma unroll
            for (int t = 0; t < TI; ++t) {
                if constexpr (AFP32) {
                    float4 f0 = *(const float4*)(apf[t] + ko);
                    float4 f1 = *(const float4*)(apf[t] + ko + 4);
                    union { uint4 u; shortx8 s; } cv;
                    cv.u = make_uint4(pack2(f0.x, f0.y), pack2(f0.z, f0.w),
                                      pack2(f1.x, f1.y), pack2(f1.z, f1.w));
                    af[t] = cv.s;
                } else {
                    af[t] = *(const shortx8*)(apb[t] + ko);
                }
            }
#pragma unroll
            for (int ti = 0; ti < TI; ++ti)
#pragma unroll
                for (int tj = 0; tj < TJ; ++tj)
                    acc[ti][tj] = __builtin_amdgcn_mfma_f32_16x16x32_bf16(bfr[tj], af[ti], acc[ti][tj], 0, 0, 0);
        }
    }

    // epilogue (transposed D): m = col = lr-indexed, n = row = lq*4 + reg
#pragma unroll
    for (int ti = 0; ti < TI; ++ti) {
        int m = m0 + wm * (BM / 2) + ti * 16 + lr;
        if (m >= M) continue;
        if (OUTMODE == 0) {
            float* Crow = (float*)Cv + (size_t)m * 256;
#pragma unroll
            for (int tj = 0; tj < TJ; ++tj) {
                int nb = n0 + wn * (BN / 2) + tj * 16 + lq * 4;
                float4 bv = *(const float4*)(bias + nb);
                float4 o = make_float4(acc[ti][tj][0] + bv.x, acc[ti][tj][1] + bv.y,
                                       acc[ti][tj][2] + bv.z, acc[ti][tj][3] + bv.w);
                *(float4*)(Crow + nb) = o;
            }
        } else {
            int b = m >= LV ? 1 : 0;
            int lv = m - (b ? LV : 0);
#pragma unroll
            for (int tj = 0; tj < TJ; ++tj) {
                int nb = n0 + wn * (BN / 2) + tj * 16 + lq * 4;
                float4 bv = *(const float4*)(bias + nb);
                int h = nb >> 5, dh = nb & 31;
                unsigned short* dst = (unsigned short*)Cv + ((size_t)(b * 8 + h) * LV + lv) * 32 + dh;
                *(uint2*)dst = make_uint2(pack2(acc[ti][tj][0] + bv.x, acc[ti][tj][1] + bv.y),
                                          pack2(acc[ti][tj][2] + bv.z, acc[ti][tj][3] + bv.w));
            }
        }
    }
}

// ---------------- K2: fp32 tiled GEMM (logits, accuracy-critical) ----------------
__global__ __launch_bounds__(256) void gemm_nt_bias(
    const float* __restrict__ A, const float* __restrict__ W,
    const float* __restrict__ bias, float* __restrict__ C, int M)
{
    const int K = 256, N = 256;
    __shared__ float As[16][68];
    __shared__ float Bs[16][68];
    int tid = threadIdx.x;
    int tcol = tid & 15, trow = tid >> 4;
    int m0 = blockIdx.x * 64, n0 = blockIdx.y * 64;
    int lr = tid >> 2, lc = (tid & 3) << 2;
    float acc[4][4] = {};
    for (int k0 = 0; k0 < K; k0 += 16) {
        int arow = m0 + lr; if (arow > M - 1) arow = M - 1;
        float4 av = *(const float4*)(A + (size_t)arow * K + k0 + lc);
        float4 wv = *(const float4*)(W + (size_t)(n0 + lr) * K + k0 + lc);
        __syncthreads();
        As[lc + 0][lr] = av.x; As[lc + 1][lr] = av.y; As[lc + 2][lr] = av.z; As[lc + 3][lr] = av.w;
        Bs[lc + 0][lr] = wv.x; Bs[lc + 1][lr] = wv.y; Bs[lc + 2][lr] = wv.z; Bs[lc + 3][lr] = wv.w;
        __syncthreads();
#pragma unroll
        for (int k = 0; k < 16; ++k) {
            float4 a4 = *(const float4*)&As[k][trow << 2];
            float4 b4 = *(const float4*)&Bs[k][tcol << 2];
            float a[4] = {a4.x, a4.y, a4.z, a4.w};
            float bb[4] = {b4.x, b4.y, b4.z, b4.w};
#pragma unroll
            for (int i = 0; i < 4; i++)
#pragma unroll
                for (int j = 0; j < 4; j++) acc[i][j] += a[i] * bb[j];
        }
    }
#pragma unroll
    for (int i = 0; i < 4; i++) {
        int m = m0 + trow * 4 + i;
        if (m >= M) continue;
#pragma unroll
        for (int j = 0; j < 4; j++) {
            int n = n0 + tcol * 4 + j;
            C[(size_t)m * N + n] = acc[i][j] + bias[n];
        }
    }
}

// ---------------- K3: XCD-temporal fused decode + bilinear gather ----------------
// grid (16, LQ/8). Linear block id lin = y*16+x round-robins XCDs (xcd=lin%8).
// Remap so XCD k processes slice k for c in [0,LQ/8), THEN slice k+8:
//   seq = lin>>3; c = seq % (LQ/8); s = (lin&7) + 8*(seq / (LQ/8)).
// Instantaneous per-XCD V working set: one 2.26 MB slice (< 4 MB L2).
__global__ __launch_bounds__(256) void decode_sample_kernel(
    const unsigned short* __restrict__ v,   // bf16 [b*8+h][LV][32]
    const float* __restrict__ logits,       // MQ x 256 (240 real)
    const float* __restrict__ ref_windows,  // MQ x 7
    float* __restrict__ attn_out,           // MQ x 200
    unsigned short* __restrict__ ohbf,      // MQ x 256 bf16
    const int* __restrict__ Hf_p, const int* __restrict__ Wf_p, int LV, int LQ)
{
    __shared__ float lg[8][32];
    __shared__ float rw[8][7];
    __shared__ float prm[8][6];
    __shared__ float mxinv[8][2];
    __shared__ uint4 pk[8][25][2];   // [q][point][colhalf] = {w_row0, w_row1, off0, off1}

    const int lin = blockIdx.y * 16 + blockIdx.x;
    const int nc = gridDim.y;               // LQ/8
    const int seq = lin >> 3;
    const int c = seq % nc;
    const int s = (lin & 7) + ((seq / nc) << 3);
    const int b = s >> 3, h = s & 7;
    const int tid = threadIdx.x;
    const int Hf = *Hf_p, Wf = *Wf_p;
    const size_t mbase = (size_t)b * LQ + c * 8;

    if (tid < 240) {
        int qq = tid / 30, j = tid - qq * 30;
        int col = (j < 25) ? h * 25 + j : 200 + h * 5 + (j - 25);
        lg[qq][j] = logits[(mbase + qq) * 256 + col];
    }
    // separate if (NOT else-if): only 256 threads in the block
    if (tid < 56) {
        int qq = tid / 7, k = tid - qq * 7;
        rw[qq][k] = ref_windows[(mbase + qq) * 7 + k];
    }
    __syncthreads();

    if (tid < 8) {
        int qq = tid;
        float mx = -1e30f;
#pragma unroll
        for (int p = 0; p < 25; p++) mx = fmaxf(mx, lg[qq][p]);
        float ssum = 0.f;
#pragma unroll
        for (int p = 0; p < 25; p++) ssum += expf(lg[qq][p] - mx);
        mxinv[qq][0] = mx; mxinv[qq][1] = 1.f / ssum;
        float cx = rw[qq][0] + lg[qq][25] * 0.125f * rw[qq][3];
        float cy = rw[qq][1] + lg[qq][26] * 0.125f * rw[qq][4];
        float bw = rw[qq][3] + lg[qq][27] * 0.125f * rw[qq][3];
        float bh = rw[qq][4] + lg[qq][28] * 0.125f * rw[qq][4];
        float ang = (rw[qq][6] + lg[qq][29] * 0.0625f) * 6.283185307179586f;
        prm[qq][0] = cx; prm[qq][1] = cy;
        prm[qq][2] = fmaxf(bw, 0.f); prm[qq][3] = fmaxf(bh, 0.f);
        prm[qq][4] = cosf(ang); prm[qq][5] = sinf(ang);
    }
    __syncthreads();

    if (tid < 200) {
        int qq = tid / 25, p = tid - qq * 25;
        float a = expf(lg[qq][p] - mxinv[qq][0]) * mxinv[qq][1];
        attn_out[(mbase + qq) * 200 + h * 25 + p] = a;
        int pi = p / 5, pj = p - pi * 5;
        float g0 = (float)(pj - 2) * 0.2f * prm[qq][2];
        float g1 = (float)(pi - 2) * 0.2f * prm[qq][3];
        float ca = prm[qq][4], sa = prm[qq][5];
        float gx = (prm[qq][0] + g0 * ca - g1 * sa) * (float)Wf - 0.5f;
        float gy = (prm[qq][1] + g0 * sa + g1 * ca) * (float)Hf - 0.5f;
        float x0f = floorf(gx), y0f = floorf(gy);
        int x0 = (int)x0f, y0 = (int)y0f;
        float wx1 = gx - x0f, wy1 = gy - y0f;
        float wx0 = 1.f - wx1, wy0 = 1.f - wy1;
        int y1 = y0 + 1;
        int bx; float wl, wr;
        if (x0 >= 0 && x0 <= Wf - 2)      { bx = x0;     wl = wx0; wr = wx1; }
        else if (x0 == -1)                { bx = 0;      wl = wx1; wr = 0.f; }
        else if (x0 == Wf - 1)            { bx = Wf - 2; wl = 0.f; wr = wx0; }
        else                              { bx = 0;      wl = 0.f; wr = 0.f; }
        float wy0v = (y0 >= 0 && y0 < Hf) ? wy0 : 0.f;
        float wy1v = (y1 >= 0 && y1 < Hf) ? wy1 : 0.f;
        int cy0 = min(max(y0, 0), Hf - 1), cy1 = min(max(y1, 0), Hf - 1);
        unsigned off0 = (unsigned)(cy0 * Wf + bx) * 16u;
        unsigned off1 = (unsigned)(cy1 * Wf + bx) * 16u;
        float aw0 = a * wy0v, aw1 = a * wy1v;
        pk[qq][p][0] = make_uint4(__float_as_uint(aw0 * wl), __float_as_uint(aw1 * wl), off0, off1);
        pk[qq][p][1] = make_uint4(__float_as_uint(aw0 * wr), __float_as_uint(aw1 * wr), off0, off1);
    }
    __syncthreads();

    const int qq = tid >> 5, l = tid & 31;
    const unsigned int* vw = (const unsigned int*)(v + (size_t)s * LV * 32);
    const uint4* pkp = &pk[qq][0][l >> 4];
    float e0 = 0.f, o0 = 0.f, e1 = 0.f, o1 = 0.f;
#pragma unroll
    for (int p = 0; p < 25; ++p) {
        uint4 t = pkp[2 * p];                 // ds_read_b128
        float w0 = __uint_as_float(t.x), w1 = __uint_as_float(t.y);
        unsigned u0 = vw[t.z + l];
        unsigned u1 = vw[t.w + l];
        e0 += w0 * __uint_as_float(u0 << 16);
        o0 += w0 * __uint_as_float(u0 & 0xffff0000u);
        e1 += w1 * __uint_as_float(u1 << 16);
        o1 += w1 * __uint_as_float(u1 & 0xffff0000u);
    }
    float a0 = e0 + e1, a1 = o0 + o1;
    a0 += __shfl_xor(a0, 16, 32);
    a1 += __shfl_xor(a1, 16, 32);
    if (l < 16)
        ((unsigned int*)ohbf)[(mbase + qq) * 128 + h * 16 + l] = pack2(a0, a1);
}

extern "C" void kernel_launch(void* const* d_in, const int* in_sizes, int n_in,
                              void* d_out, int out_size, void* d_ws, size_t ws_size,
                              hipStream_t stream) {
    const float* query       = (const float*)d_in[0];
    const float* value       = (const float*)d_in[1];
    const float* ref_windows = (const float*)d_in[2];
    const float* W_box       = (const float*)d_in[3];
    const float* b_box       = (const float*)d_in[4];
    const float* W_attn      = (const float*)d_in[5];
    const float* b_attn      = (const float*)d_in[6];
    const float* W_value     = (const float*)d_in[7];
    const float* b_value     = (const float*)d_in[8];
    const float* W_out       = (const float*)d_in[9];
    const float* b_out       = (const float*)d_in[10];
    const int*   Hf          = (const int*)d_in[11];
    const int*   Wf          = (const int*)d_in[12];

    const int M1 = in_sizes[1] / 256;  // B*LV = 70688
    const int MQ = in_sizes[0] / 256;  // B*LQ = 8192
    const int LQ = MQ / 2;
    const int LV = M1 / 2;

    unsigned short* Vout = (unsigned short*)d_ws;                 // M1*256
    unsigned short* ohbf = Vout + (size_t)M1 * 256;               // MQ*256
    unsigned short* wvbf = ohbf + (size_t)MQ * 256;               // 65536
    unsigned short* wobf = wvbf + 65536;                          // 65536
    float* Wab       = (float*)(wobf + 65536);                    // 65536 fp32
    float* bab       = Wab + 65536;                               // 256
    float* logits    = bab + 256;                                 // MQ*256

    float* out0     = (float*)d_out;
    float* attn_out = out0 + (size_t)MQ * 256;

    // K0: weight conversions (16 + 16 + 16 + 1 = 49 blocks)
    convert_kernel<<<49, 256, 0, stream>>>(W_value, wvbf, W_attn, W_box, Wab,
                                           W_out, wobf, b_attn, b_box, bab);
    // K1: value projection, no-LDS direct GEMM -> head-major bf16 Vout
    dim3 g1((M1 + 63) / 64, 1);
    gemm_direct<1, 1, 64, 256><<<g1, 256, 0, stream>>>(value, wvbf, b_value, Vout, M1, LV);
    // K2: logits fp32 (accuracy-critical box path)
    dim3 g2(MQ / 64, 4);
    gemm_nt_bias<<<g2, 256, 0, stream>>>(query, Wab, bab, logits, MQ);
    // K3: XCD-temporal fused softmax + box decode + gather -> bf16 out_heads
    decode_sample_kernel<<<dim3(16, LQ / 8), 256, 0, stream>>>(
        Vout, logits, ref_windows, attn_out, ohbf, Hf, Wf, LV, LQ);
    // K4: output projection, no-LDS direct GEMM (grid (128,2)=256 blocks)
    dim3 g4((MQ + 63) / 64, 2);
    gemm_direct<0, 0, 64, 128><<<g4, 256, 0, stream>>>(ohbf, wobf, b_out, out0, MQ, LV);
}

// Round 6
// 229.243 us; speedup vs baseline: 1.0971x; 1.0971x over previous
//
#include <hip/hip_runtime.h>

// Box3dAttention: B=2, LQ=4096, d=256, heads=8, head_dim=32, 5x5=25 points,
// feature map 188x188 (LV=35344).
//
// Round 14:
//  (a) K1 rewritten as gemm_vproj: B (256x256 bf16 weights) fully resident in
//      LDS (one-time stage, ONE barrier), then a barrier-free grid-stride loop
//      over 64-row m-tiles. 8 waves (4n x 2m), wave tile 32x64 -> acc only 32
//      VGPR (round-13's VGPR=100 showed big acc starved load pipelining).
//      LDS row stride 528B (16B pad) -> word stride 132 == 4 mod 32 ->
//      bank-balanced ds_read_b128 (8 lanes/4-bank group = the 1KB/128B floor).
//      A fp32 read exactly once (BN=256, no n-split duplication), f2bf in-reg.
//  (b) K4 reverted to the verified round-11 LDS dbuf+swizzle kernel (BM=64).
//  (c) K0/K2/K3 unchanged. All math orders identical -> bitwise-same outputs.
//
// Pipeline:
//  K0 convert    : W_value/W_out -> bf16, [W_attn;W_box] -> fp32 pad, bias pad
//  K1 gemm_vproj : value fp32 @ wvbf^T + b_value -> Vout bf16 head-major
//  K2 gemm_nt    : fp32 VALU logits = query @ [W_attn;W_box]^T + b
//  K3 decode_sample: XCD-temporal remap fused decode+gather
//  K4 gemm_out   : ohbf @ wobf^T + b_out -> out fp32

typedef float floatx4 __attribute__((ext_vector_type(4)));
typedef short shortx8 __attribute__((ext_vector_type(8)));

static __device__ __forceinline__ unsigned short f2bf(float x) {
    unsigned int u = __float_as_uint(x);
    return (unsigned short)((u + 0x7fffu + ((u >> 16) & 1u)) >> 16);
}
static __device__ __forceinline__ unsigned int pack2(float a, float b) {
    return (unsigned int)f2bf(a) | ((unsigned int)f2bf(b) << 16);
}
static __device__ __forceinline__ void async16(const void* g, void* lds) {
    __builtin_amdgcn_global_load_lds(
        (const __attribute__((address_space(1))) unsigned int*)g,
        (__attribute__((address_space(3))) unsigned int*)lds, 16, 0, 0);
}

// ---------------- K0: weight/bias conversions only ----------------
// grid = 16 (W_value) + 16 (Wab fp32 pad) + 16 (W_out) + 1 (bias) = 49
__global__ __launch_bounds__(256) void convert_kernel(
    const float* __restrict__ W_value, unsigned short* __restrict__ wvbf,
    const float* __restrict__ W_attn, const float* __restrict__ W_box,
    float* __restrict__ Wab,
    const float* __restrict__ W_out, unsigned short* __restrict__ wobf,
    const float* __restrict__ b_attn, const float* __restrict__ b_box,
    float* __restrict__ bab)
{
    const int blk = blockIdx.x, tid = threadIdx.x;
    if (blk < 16) {
        int base = blk * 1024 + tid;
#pragma unroll
        for (int k = 0; k < 4; ++k) {
            int j = base + k * 256;
            float4 f = ((const float4*)W_value)[j];
            ((uint2*)wvbf)[j] = make_uint2(pack2(f.x, f.y), pack2(f.z, f.w));
        }
    } else if (blk < 32) {
        int base = (blk - 16) * 1024 + tid;
#pragma unroll
        for (int k = 0; k < 4; ++k) {
            int j = base + k * 256;
            int row = j >> 6, col = (j & 63) * 4;
            float4 f;
            if (row < 200)      f = *(const float4*)(W_attn + (size_t)row * 256 + col);
            else if (row < 240) f = *(const float4*)(W_box + (size_t)(row - 200) * 256 + col);
            else                f = make_float4(0.f, 0.f, 0.f, 0.f);
            ((float4*)Wab)[j] = f;
        }
    } else if (blk < 48) {
        int base = (blk - 32) * 1024 + tid;
#pragma unroll
        for (int k = 0; k < 4; ++k) {
            int j = base + k * 256;
            float4 f = ((const float4*)W_out)[j];
            ((uint2*)wobf)[j] = make_uint2(pack2(f.x, f.y), pack2(f.z, f.w));
        }
    } else {
        bab[tid] = tid < 200 ? b_attn[tid] : (tid < 240 ? b_box[tid - 200] : 0.f);
    }
}

// ---------------- K1: B-resident barrier-free value projection ----------------
// Vout = value(M x 256 fp32) @ wvbf(256 x 256 bf16)^T + b_value, head-major bf16.
// 512 threads = 8 waves (wn=wv&3 n-quarter, wm=wv>>2 m-half). One-time B stage
// into LDS [256][264] shorts (528B stride), single barrier, then grid-stride
// m-loop with ZERO barriers. acc 2x4 floatx4 = 32 VGPR/lane.
__global__ __launch_bounds__(512) void gemm_vproj(
    const float* __restrict__ A,            // M x 256 fp32 (value)
    const unsigned short* __restrict__ Bw,  // 256 x 256 bf16 (wvbf)
    const float* __restrict__ bias,
    unsigned short* __restrict__ Vout, int M, int LV)
{
    __shared__ unsigned short Bs[256 * 264];   // 135168 B
    const int tid = threadIdx.x;
    const int wv = tid >> 6, lane = tid & 63;
    const int lr = lane & 15, lq = lane >> 4;
    const int wn = wv & 3, wm = wv >> 2;

    // one-time B staging: 8192 granules of 16B, coalesced global reads
#pragma unroll
    for (int it = 0; it < 16; ++it) {
        int j = it * 512 + tid;
        int row = j >> 5, gc = j & 31;
        uint4 v = *(const uint4*)(Bw + (size_t)row * 256 + gc * 8);
        *(uint4*)((char*)Bs + row * 528 + gc * 16) = v;
    }
    __syncthreads();

    // per-lane B LDS byte bases (t = n-frag); per-ks offset = ks*64 immediate
    int bbase[4];
#pragma unroll
    for (int t = 0; t < 4; ++t) {
        int rb = wn * 64 + t * 16 + lr;
        bbase[t] = rb * 528 + lq * 16;
    }

    const int niter = (M + 63) / 64;
    for (int it = blockIdx.x; it < niter; it += gridDim.x) {
        const float* ap[2];
#pragma unroll
        for (int t = 0; t < 2; ++t) {
            int ra = it * 64 + wm * 32 + t * 16 + lr;
            ra = ra < M ? ra : M - 1;
            ap[t] = A + (size_t)ra * 256 + lq * 8;
        }
        floatx4 acc[2][4];
#pragma unroll
        for (int i = 0; i < 2; ++i)
#pragma unroll
            for (int j = 0; j < 4; ++j) acc[i][j] = (floatx4){0.f, 0.f, 0.f, 0.f};

#pragma unroll
        for (int ks = 0; ks < 8; ++ks) {
            shortx8 af[2], bf[4];
#pragma unroll
            for (int t = 0; t < 4; ++t)
                bf[t] = *(const shortx8*)((const char*)Bs + bbase[t] + ks * 64);
#pragma unroll
            for (int t = 0; t < 2; ++t) {
                float4 f0 = *(const float4*)(ap[t] + ks * 32);
                float4 f1 = *(const float4*)(ap[t] + ks * 32 + 4);
                union { uint4 u; shortx8 s; } cv;
                cv.u = make_uint4(pack2(f0.x, f0.y), pack2(f0.z, f0.w),
                                  pack2(f1.x, f1.y), pack2(f1.z, f1.w));
                af[t] = cv.s;
            }
#pragma unroll
            for (int ti = 0; ti < 2; ++ti)
#pragma unroll
                for (int tj = 0; tj < 4; ++tj)
                    acc[ti][tj] = __builtin_amdgcn_mfma_f32_16x16x32_bf16(bf[tj], af[ti], acc[ti][tj], 0, 0, 0);
        }
        // epilogue (transposed D): m = lr-indexed col, n = lq*4 + reg
#pragma unroll
        for (int ti = 0; ti < 2; ++ti) {
            int m = it * 64 + wm * 32 + ti * 16 + lr;
            if (m >= M) continue;
            int b = m >= LV ? 1 : 0;
            int lv = m - (b ? LV : 0);
#pragma unroll
            for (int tj = 0; tj < 4; ++tj) {
                int nb = wn * 64 + tj * 16 + lq * 4;
                float4 bv = *(const float4*)(bias + nb);
                int h = nb >> 5, dh = nb & 31;
                unsigned short* dst = Vout + ((size_t)(b * 8 + h) * LV + lv) * 32 + dh;
                *(uint2*)dst = make_uint2(pack2(acc[ti][tj][0] + bv.x, acc[ti][tj][1] + bv.y),
                                          pack2(acc[ti][tj][2] + bv.z, acc[ti][tj][3] + bv.w));
            }
        }
    }
}

// ---------------- K4: round-11 LDS dbuf+swizzle bf16 GEMM (BM=64) ----------------
// out = ohbf(M x 256 bf16) @ wobf(256 x 256 bf16)^T + b_out, fp32 row-major.
__global__ __launch_bounds__(256) void gemm_out(
    const unsigned short* __restrict__ Ab,
    const unsigned short* __restrict__ Bw,
    const float* __restrict__ bias,
    float* __restrict__ C, int M)
{
    constexpr int BM = 64;
    constexpr int NI = BM / 32, TI = BM / 32;
    __shared__ unsigned short As[2][BM * 64];
    __shared__ unsigned short Bs[2][128 * 64];
    const int tid = threadIdx.x;
    const int wv = tid >> 6, lane = tid & 63;
    const int lr = lane & 15, lq = lane >> 4;
    const int m0 = blockIdx.x * BM, n0 = blockIdx.y * 128;
    const int wm = wv & 1, wn = wv >> 1;
    const int srow = tid >> 3;
    const int colg = tid & 7;
    const int colgSw = colg ^ (srow & 7);

    floatx4 acc[TI][4];
#pragma unroll
    for (int i = 0; i < TI; ++i)
#pragma unroll
        for (int j = 0; j < 4; ++j) acc[i][j] = (floatx4){0.f, 0.f, 0.f, 0.f};

    auto compute = [&](const unsigned short* Acur, const unsigned short* Bcur) {
#pragma unroll
        for (int kb = 0; kb < 2; ++kb) {
            shortx8 af[TI], bfr[4];
#pragma unroll
            for (int t = 0; t < TI; ++t) {
                int arow = wm * (BM / 2) + t * 16 + lr;
                af[t] = *(const shortx8*)&Acur[arow * 64 + (((kb * 4 + lq) ^ (arow & 7)) * 8)];
            }
#pragma unroll
            for (int t = 0; t < 4; ++t) {
                int brow = wn * 64 + t * 16 + lr;
                bfr[t] = *(const shortx8*)&Bcur[brow * 64 + (((kb * 4 + lq) ^ (brow & 7)) * 8)];
            }
#pragma unroll
            for (int ti = 0; ti < TI; ++ti)
#pragma unroll
                for (int tj = 0; tj < 4; ++tj)
                    acc[ti][tj] = __builtin_amdgcn_mfma_f32_16x16x32_bf16(bfr[tj], af[ti], acc[ti][tj], 0, 0, 0);
        }
    };

#pragma unroll
    for (int i = 0; i < NI; ++i) {
        int ra = m0 + i * 32 + srow; ra = ra < M ? ra : M - 1;
        async16(Ab + (size_t)ra * 256 + colgSw * 8, (char*)As[0] + i * 4096 + wv * 1024);
    }
#pragma unroll
    for (int i = 0; i < 4; ++i) {
        int rb = n0 + i * 32 + srow;
        async16(Bw + (size_t)rb * 256 + colgSw * 8, (char*)Bs[0] + i * 4096 + wv * 1024);
    }
    __syncthreads();
    int cur = 0;
    for (int kc = 0; kc < 4; ++kc) {
        const int nk = (kc + 1) * 64;
        if (kc < 3) {
#pragma unroll
            for (int i = 0; i < NI; ++i) {
                int ra = m0 + i * 32 + srow; ra = ra < M ? ra : M - 1;
                async16(Ab + (size_t)ra * 256 + nk + colgSw * 8,
                        (char*)As[cur ^ 1] + i * 4096 + wv * 1024);
            }
#pragma unroll
            for (int i = 0; i < 4; ++i) {
                int rb = n0 + i * 32 + srow;
                async16(Bw + (size_t)rb * 256 + nk + colgSw * 8,
                        (char*)Bs[cur ^ 1] + i * 4096 + wv * 1024);
            }
        }
        compute(As[cur], Bs[cur]);
        __syncthreads();
        cur ^= 1;
    }
#pragma unroll
    for (int ti = 0; ti < TI; ++ti) {
        int m = m0 + wm * (BM / 2) + ti * 16 + lr;
        if (m >= M) continue;
        float* Crow = C + (size_t)m * 256;
#pragma unroll
        for (int tj = 0; tj < 4; ++tj) {
            int nb = n0 + wn * 64 + tj * 16 + lq * 4;
            float4 bv = *(const float4*)(bias + nb);
            float4 o = make_float4(acc[ti][tj][0] + bv.x, acc[ti][tj][1] + bv.y,
                                   acc[ti][tj][2] + bv.z, acc[ti][tj][3] + bv.w);
            *(float4*)(Crow + nb) = o;
        }
    }
}

// ---------------- K2: fp32 tiled GEMM (logits, accuracy-critical) ----------------
__global__ __launch_bounds__(256) void gemm_nt_bias(
    const float* __restrict__ A, const float* __restrict__ W,
    const float* __restrict__ bias, float* __restrict__ C, int M)
{
    const int K = 256, N = 256;
    __shared__ float As[16][68];
    __shared__ float Bs[16][68];
    int tid = threadIdx.x;
    int tcol = tid & 15, trow = tid >> 4;
    int m0 = blockIdx.x * 64, n0 = blockIdx.y * 64;
    int lr = tid >> 2, lc = (tid & 3) << 2;
    float acc[4][4] = {};
    for (int k0 = 0; k0 < K; k0 += 16) {
        int arow = m0 + lr; if (arow > M - 1) arow = M - 1;
        float4 av = *(const float4*)(A + (size_t)arow * K + k0 + lc);
        float4 wv = *(const float4*)(W + (size_t)(n0 + lr) * K + k0 + lc);
        __syncthreads();
        As[lc + 0][lr] = av.x; As[lc + 1][lr] = av.y; As[lc + 2][lr] = av.z; As[lc + 3][lr] = av.w;
        Bs[lc + 0][lr] = wv.x; Bs[lc + 1][lr] = wv.y; Bs[lc + 2][lr] = wv.z; Bs[lc + 3][lr] = wv.w;
        __syncthreads();
#pragma unroll
        for (int k = 0; k < 16; ++k) {
            float4 a4 = *(const float4*)&As[k][trow << 2];
            float4 b4 = *(const float4*)&Bs[k][tcol << 2];
            float a[4] = {a4.x, a4.y, a4.z, a4.w};
            float bb[4] = {b4.x, b4.y, b4.z, b4.w};
#pragma unroll
            for (int i = 0; i < 4; i++)
#pragma unroll
                for (int j = 0; j < 4; j++) acc[i][j] += a[i] * bb[j];
        }
    }
#pragma unroll
    for (int i = 0; i < 4; i++) {
        int m = m0 + trow * 4 + i;
        if (m >= M) continue;
#pragma unroll
        for (int j = 0; j < 4; j++) {
            int n = n0 + tcol * 4 + j;
            C[(size_t)m * N + n] = acc[i][j] + bias[n];
        }
    }
}

// ---------------- K3: XCD-temporal fused decode + bilinear gather ----------------
__global__ __launch_bounds__(256) void decode_sample_kernel(
    const unsigned short* __restrict__ v,   // bf16 [b*8+h][LV][32]
    const float* __restrict__ logits,       // MQ x 256 (240 real)
    const float* __restrict__ ref_windows,  // MQ x 7
    float* __restrict__ attn_out,           // MQ x 200
    unsigned short* __restrict__ ohbf,      // MQ x 256 bf16
    const int* __restrict__ Hf_p, const int* __restrict__ Wf_p, int LV, int LQ)
{
    __shared__ float lg[8][32];
    __shared__ float rw[8][7];
    __shared__ float prm[8][6];
    __shared__ float mxinv[8][2];
    __shared__ uint4 pk[8][25][2];

    const int lin = blockIdx.y * 16 + blockIdx.x;
    const int nc = gridDim.y;               // LQ/8
    const int seq = lin >> 3;
    const int c = seq % nc;
    const int s = (lin & 7) + ((seq / nc) << 3);
    const int b = s >> 3, h = s & 7;
    const int tid = threadIdx.x;
    const int Hf = *Hf_p, Wf = *Wf_p;
    const size_t mbase = (size_t)b * LQ + c * 8;

    if (tid < 240) {
        int qq = tid / 30, j = tid - qq * 30;
        int col = (j < 25) ? h * 25 + j : 200 + h * 5 + (j - 25);
        lg[qq][j] = logits[(mbase + qq) * 256 + col];
    }
    if (tid < 56) {
        int qq = tid / 7, k = tid - qq * 7;
        rw[qq][k] = ref_windows[(mbase + qq) * 7 + k];
    }
    __syncthreads();

    if (tid < 8) {
        int qq = tid;
        float mx = -1e30f;
#pragma unroll
        for (int p = 0; p < 25; p++) mx = fmaxf(mx, lg[qq][p]);
        float ssum = 0.f;
#pragma unroll
        for (int p = 0; p < 25; p++) ssum += expf(lg[qq][p] - mx);
        mxinv[qq][0] = mx; mxinv[qq][1] = 1.f / ssum;
        float cx = rw[qq][0] + lg[qq][25] * 0.125f * rw[qq][3];
        float cy = rw[qq][1] + lg[qq][26] * 0.125f * rw[qq][4];
        float bw = rw[qq][3] + lg[qq][27] * 0.125f * rw[qq][3];
        float bh = rw[qq][4] + lg[qq][28] * 0.125f * rw[qq][4];
        float ang = (rw[qq][6] + lg[qq][29] * 0.0625f) * 6.283185307179586f;
        prm[qq][0] = cx; prm[qq][1] = cy;
        prm[qq][2] = fmaxf(bw, 0.f); prm[qq][3] = fmaxf(bh, 0.f);
        prm[qq][4] = cosf(ang); prm[qq][5] = sinf(ang);
    }
    __syncthreads();

    if (tid < 200) {
        int qq = tid / 25, p = tid - qq * 25;
        float a = expf(lg[qq][p] - mxinv[qq][0]) * mxinv[qq][1];
        attn_out[(mbase + qq) * 200 + h * 25 + p] = a;
        int pi = p / 5, pj = p - pi * 5;
        float g0 = (float)(pj - 2) * 0.2f * prm[qq][2];
        float g1 = (float)(pi - 2) * 0.2f * prm[qq][3];
        float ca = prm[qq][4], sa = prm[qq][5];
        float gx = (prm[qq][0] + g0 * ca - g1 * sa) * (float)Wf - 0.5f;
        float gy = (prm[qq][1] + g0 * sa + g1 * ca) * (float)Hf - 0.5f;
        float x0f = floorf(gx), y0f = floorf(gy);
        int x0 = (int)x0f, y0 = (int)y0f;
        float wx1 = gx - x0f, wy1 = gy - y0f;
        float wx0 = 1.f - wx1, wy0 = 1.f - wy1;
        int y1 = y0 + 1;
        int bx; float wl, wr;
        if (x0 >= 0 && x0 <= Wf - 2)      { bx = x0;     wl = wx0; wr = wx1; }
        else if (x0 == -1)                { bx = 0;      wl = wx1; wr = 0.f; }
        else if (x0 == Wf - 1)            { bx = Wf - 2; wl = 0.f; wr = wx0; }
        else                              { bx = 0;      wl = 0.f; wr = 0.f; }
        float wy0v = (y0 >= 0 && y0 < Hf) ? wy0 : 0.f;
        float wy1v = (y1 >= 0 && y1 < Hf) ? wy1 : 0.f;
        int cy0 = min(max(y0, 0), Hf - 1), cy1 = min(max(y1, 0), Hf - 1);
        unsigned off0 = (unsigned)(cy0 * Wf + bx) * 16u;
        unsigned off1 = (unsigned)(cy1 * Wf + bx) * 16u;
        float aw0 = a * wy0v, aw1 = a * wy1v;
        pk[qq][p][0] = make_uint4(__float_as_uint(aw0 * wl), __float_as_uint(aw1 * wl), off0, off1);
        pk[qq][p][1] = make_uint4(__float_as_uint(aw0 * wr), __float_as_uint(aw1 * wr), off0, off1);
    }
    __syncthreads();

    const int qq = tid >> 5, l = tid & 31;
    const unsigned int* vw = (const unsigned int*)(v + (size_t)s * LV * 32);
    const uint4* pkp = &pk[qq][0][l >> 4];
    float e0 = 0.f, o0 = 0.f, e1 = 0.f, o1 = 0.f;
#pragma unroll
    for (int p = 0; p < 25; ++p) {
        uint4 t = pkp[2 * p];
        float w0 = __uint_as_float(t.x), w1 = __uint_as_float(t.y);
        unsigned u0 = vw[t.z + l];
        unsigned u1 = vw[t.w + l];
        e0 += w0 * __uint_as_float(u0 << 16);
        o0 += w0 * __uint_as_float(u0 & 0xffff0000u);
        e1 += w1 * __uint_as_float(u1 << 16);
        o1 += w1 * __uint_as_float(u1 & 0xffff0000u);
    }
    float a0 = e0 + e1, a1 = o0 + o1;
    a0 += __shfl_xor(a0, 16, 32);
    a1 += __shfl_xor(a1, 16, 32);
    if (l < 16)
        ((unsigned int*)ohbf)[(mbase + qq) * 128 + h * 16 + l] = pack2(a0, a1);
}

extern "C" void kernel_launch(void* const* d_in, const int* in_sizes, int n_in,
                              void* d_out, int out_size, void* d_ws, size_t ws_size,
                              hipStream_t stream) {
    const float* query       = (const float*)d_in[0];
    const float* value       = (const float*)d_in[1];
    const float* ref_windows = (const float*)d_in[2];
    const float* W_box       = (const float*)d_in[3];
    const float* b_box       = (const float*)d_in[4];
    const float* W_attn      = (const float*)d_in[5];
    const float* b_attn      = (const float*)d_in[6];
    const float* W_value     = (const float*)d_in[7];
    const float* b_value     = (const float*)d_in[8];
    const float* W_out       = (const float*)d_in[9];
    const float* b_out       = (const float*)d_in[10];
    const int*   Hf          = (const int*)d_in[11];
    const int*   Wf          = (const int*)d_in[12];

    const int M1 = in_sizes[1] / 256;  // B*LV = 70688
    const int MQ = in_sizes[0] / 256;  // B*LQ = 8192
    const int LQ = MQ / 2;
    const int LV = M1 / 2;

    unsigned short* Vout = (unsigned short*)d_ws;                 // M1*256
    unsigned short* ohbf = Vout + (size_t)M1 * 256;               // MQ*256
    unsigned short* wvbf = ohbf + (size_t)MQ * 256;               // 65536
    unsigned short* wobf = wvbf + 65536;                          // 65536
    float* Wab       = (float*)(wobf + 65536);                    // 65536 fp32
    float* bab       = Wab + 65536;                               // 256
    float* logits    = bab + 256;                                 // MQ*256

    float* out0     = (float*)d_out;
    float* attn_out = out0 + (size_t)MQ * 256;

    // K0: weight conversions
    convert_kernel<<<49, 256, 0, stream>>>(W_value, wvbf, W_attn, W_box, Wab,
                                           W_out, wobf, b_attn, b_box, bab);
    // K1: value projection, B-resident barrier-free GEMM
    gemm_vproj<<<256, 512, 0, stream>>>(value, wvbf, b_value, Vout, M1, LV);
    // K2: logits fp32 (accuracy-critical box path)
    dim3 g2(MQ / 64, 4);
    gemm_nt_bias<<<g2, 256, 0, stream>>>(query, Wab, bab, logits, MQ);
    // K3: XCD-temporal fused softmax + box decode + gather -> bf16 out_heads
    decode_sample_kernel<<<dim3(16, LQ / 8), 256, 0, stream>>>(
        Vout, logits, ref_windows, attn_out, ohbf, Hf, Wf, LV, LQ);
    // K4: output projection (round-11 verified LDS dbuf kernel)
    dim3 g4(MQ / 64, 2);
    gemm_out<<<g4, 256, 0, stream>>>(ohbf, wobf, b_out, out0, MQ);
}

// Round 7
// 229.138 us; speedup vs baseline: 1.0976x; 1.0005x over previous
//
#include <hip/hip_runtime.h>

// Box3dAttention: B=2, LQ=4096, d=256, heads=8, head_dim=32, 5x5=25 points,
// feature map 188x188 (LV=35344).
//
// Round 15 = round 11 (best verified, 212.4us) + K1/K2 FUSED into one dispatch:
//  - K1 (latency-bound MFMA, 1106 blocks) and K2 (VALU-dense fp32 logits,
//    512 blocks) are data-independent (value vs query). Serial execution
//    wastes K1's latency bubbles. One 1618-block dispatch interleaves them
//    3:1 (f%3==2 && f<1536 -> K2) so both kinds co-reside per CU; CDNA
//    schedules MFMA-waves and VALU-waves concurrently (time ~ max, not sum).
//  - Code inside each path is UNCHANGED from round 11 -> bitwise outputs.
//  - LDS: single 64KB buffer, K1 path uses all, K2 path uses 8.7KB of it.
//
// Pipeline:
//  K0 convert     : W_value/W_out -> bf16, [W_attn;W_box] -> fp32 pad, bias pad
//  K12 fused_proj : blocks A: value fp32 @ wvbf^T + b_value -> Vout bf16
//                   blocks B: fp32 VALU logits = query @ [W_attn;W_box]^T + b
//  K3 decode_sample: XCD-temporal remap fused decode+gather
//  K4 gemm_bf16<0,0,64>: ohbf @ wobf^T + b_out -> out fp32

typedef float floatx4 __attribute__((ext_vector_type(4)));
typedef short shortx8 __attribute__((ext_vector_type(8)));

#define SB0 __builtin_amdgcn_sched_barrier(0)
#define VMCNT8 asm volatile("s_waitcnt vmcnt(8)" ::: "memory")
#define VMCNT0 asm volatile("s_waitcnt vmcnt(0)" ::: "memory")
#define LGKM0  asm volatile("s_waitcnt lgkmcnt(0)" ::: "memory")

static __device__ __forceinline__ unsigned short f2bf(float x) {
    unsigned int u = __float_as_uint(x);
    return (unsigned short)((u + 0x7fffu + ((u >> 16) & 1u)) >> 16);
}
static __device__ __forceinline__ unsigned int pack2(float a, float b) {
    return (unsigned int)f2bf(a) | ((unsigned int)f2bf(b) << 16);
}
static __device__ __forceinline__ void async16(const void* g, void* lds) {
    __builtin_amdgcn_global_load_lds(
        (const __attribute__((address_space(1))) unsigned int*)g,
        (__attribute__((address_space(3))) unsigned int*)lds, 16, 0, 0);
}

// ---------------- K0: weight/bias conversions only ----------------
__global__ __launch_bounds__(256) void convert_kernel(
    const float* __restrict__ W_value, unsigned short* __restrict__ wvbf,
    const float* __restrict__ W_attn, const float* __restrict__ W_box,
    float* __restrict__ Wab,
    const float* __restrict__ W_out, unsigned short* __restrict__ wobf,
    const float* __restrict__ b_attn, const float* __restrict__ b_box,
    float* __restrict__ bab)
{
    const int blk = blockIdx.x, tid = threadIdx.x;
    if (blk < 16) {
        int base = blk * 1024 + tid;
#pragma unroll
        for (int k = 0; k < 4; ++k) {
            int j = base + k * 256;
            float4 f = ((const float4*)W_value)[j];
            ((uint2*)wvbf)[j] = make_uint2(pack2(f.x, f.y), pack2(f.z, f.w));
        }
    } else if (blk < 32) {
        int base = (blk - 16) * 1024 + tid;
#pragma unroll
        for (int k = 0; k < 4; ++k) {
            int j = base + k * 256;
            int row = j >> 6, col = (j & 63) * 4;
            float4 f;
            if (row < 200)      f = *(const float4*)(W_attn + (size_t)row * 256 + col);
            else if (row < 240) f = *(const float4*)(W_box + (size_t)(row - 200) * 256 + col);
            else                f = make_float4(0.f, 0.f, 0.f, 0.f);
            ((float4*)Wab)[j] = f;
        }
    } else if (blk < 48) {
        int base = (blk - 32) * 1024 + tid;
#pragma unroll
        for (int k = 0; k < 4; ++k) {
            int j = base + k * 256;
            float4 f = ((const float4*)W_out)[j];
            ((uint2*)wobf)[j] = make_uint2(pack2(f.x, f.y), pack2(f.z, f.w));
        }
    } else {
        bab[tid] = tid < 200 ? b_attn[tid] : (tid < 240 ? b_box[tid - 200] : 0.f);
    }
}

// ---------------- K12: fused value-projection + logits ----------------
// Block roles: f%3==2 && f<1536 -> K2 (512 blocks); else K1 (1106 blocks).
// K1 path == round-11 gemm_bf16<1,1,128> (hand-scheduled pipeline, swizzle).
// K2 path == round-11 gemm_nt_bias. Both bitwise-identical to round 11.
__global__ __launch_bounds__(256) void fused_proj(
    const float* __restrict__ value,
    const unsigned short* __restrict__ wvbf,
    const float* __restrict__ b_value,
    unsigned short* __restrict__ Vout, int M1, int LV,
    const float* __restrict__ query,
    const float* __restrict__ Wab,
    const float* __restrict__ bab,
    float* __restrict__ logits, int MQ)
{
    __shared__ char smem[65536];
    const int f = blockIdx.x;
    const int tid = threadIdx.x;
    const bool isK2 = (f % 3 == 2) && (f < 1536);

    if (!isK2) {
        // ---------------- K1: value projection (round-11 pipeline) ----------
        const int k1id = f - ((f < 1536) ? ((f + 1) / 3) : 512);
        const int bx = k1id % 553, by = k1id / 553;
        unsigned short* AsL = (unsigned short*)smem;            // [2][8192]
        unsigned short* BsL = (unsigned short*)smem + 16384;    // [2][8192]
        const int wv = tid >> 6, lane = tid & 63;
        const int lr = lane & 15, lq = lane >> 4;
        const int m0 = bx * 128, n0 = by * 128;
        const int wm = wv & 1, wn = wv >> 1;
        const int srow = tid >> 3;
        const int colg = tid & 7;
        const int colgSw = colg ^ (srow & 7);
        const int dstA = (srow * 8 + colgSw) * 16;
        const int M = M1;

        floatx4 acc[4][4];
#pragma unroll
        for (int i = 0; i < 4; ++i)
#pragma unroll
            for (int j = 0; j < 4; ++j) acc[i][j] = (floatx4){0.f, 0.f, 0.f, 0.f};

        auto compute = [&](const unsigned short* Acur, const unsigned short* Bcur) {
#pragma unroll
            for (int kb = 0; kb < 2; ++kb) {
                shortx8 af[4], bfr[4];
#pragma unroll
                for (int t = 0; t < 4; ++t) {
                    int arow = wm * 64 + t * 16 + lr;
                    af[t] = *(const shortx8*)&Acur[arow * 64 + (((kb * 4 + lq) ^ (arow & 7)) * 8)];
                }
#pragma unroll
                for (int t = 0; t < 4; ++t) {
                    int brow = wn * 64 + t * 16 + lr;
                    bfr[t] = *(const shortx8*)&Bcur[brow * 64 + (((kb * 4 + lq) ^ (brow & 7)) * 8)];
                }
#pragma unroll
                for (int ti = 0; ti < 4; ++ti)
#pragma unroll
                    for (int tj = 0; tj < 4; ++tj)
                        acc[ti][tj] = __builtin_amdgcn_mfma_f32_16x16x32_bf16(bfr[tj], af[ti], acc[ti][tj], 0, 0, 0);
            }
        };

        const float* aptr[4];
#pragma unroll
        for (int i = 0; i < 4; ++i) {
            int ra = m0 + i * 32 + srow; ra = ra < M ? ra : M - 1;
            aptr[i] = value + (size_t)ra * 256 + colg * 8;
        }
        const unsigned short* bptr = wvbf + (size_t)(n0 + srow) * 256 + colgSw * 8;
        float4 ar0[4], ar1[4];

        // prologue: A_0 -> regs, B_0 -> LDS, pack A_0, issue A_1, drain B_0
#pragma unroll
        for (int i = 0; i < 4; ++i) { ar0[i] = *(const float4*)aptr[i]; ar1[i] = *(const float4*)(aptr[i] + 4); }
#pragma unroll
        for (int i = 0; i < 4; ++i)
            async16(bptr + (size_t)i * 8192, (char*)BsL + i * 4096 + wv * 1024);
        SB0;
#pragma unroll
        for (int i = 0; i < 4; ++i) {
            uint4 pv = make_uint4(pack2(ar0[i].x, ar0[i].y), pack2(ar0[i].z, ar0[i].w),
                                  pack2(ar1[i].x, ar1[i].y), pack2(ar1[i].z, ar1[i].w));
            *(uint4*)((char*)AsL + i * 4096 + dstA) = pv;
        }
#pragma unroll
        for (int i = 0; i < 4; ++i) { ar0[i] = *(const float4*)(aptr[i] + 64); ar1[i] = *(const float4*)(aptr[i] + 68); }
        SB0;
        VMCNT8;
        LGKM0;
        __builtin_amdgcn_s_barrier();
        SB0;

#pragma unroll
        for (int kc = 0; kc < 4; ++kc) {
            const int cur = kc & 1;
            unsigned short* Acur = AsL + cur * 8192;
            unsigned short* Anxt = AsL + (cur ^ 1) * 8192;
            unsigned short* Bcur = BsL + cur * 8192;
            unsigned short* Bnxt = BsL + (cur ^ 1) * 8192;
            if (kc < 3) {
#pragma unroll
                for (int i = 0; i < 4; ++i)
                    async16(bptr + (size_t)i * 8192 + (kc + 1) * 64,
                            (char*)Bnxt + i * 4096 + wv * 1024);
            }
            SB0;
            compute(Acur, Bcur);
            SB0;
            if (kc < 3) {
#pragma unroll
                for (int i = 0; i < 4; ++i) {
                    uint4 pv = make_uint4(pack2(ar0[i].x, ar0[i].y), pack2(ar0[i].z, ar0[i].w),
                                          pack2(ar1[i].x, ar1[i].y), pack2(ar1[i].z, ar1[i].w));
                    *(uint4*)((char*)Anxt + i * 4096 + dstA) = pv;
                }
                if (kc < 2) {
#pragma unroll
                    for (int i = 0; i < 4; ++i) {
                        ar0[i] = *(const float4*)(aptr[i] + (kc + 2) * 64);
                        ar1[i] = *(const float4*)(aptr[i] + (kc + 2) * 64 + 4);
                    }
                    SB0;
                    VMCNT8;
                } else {
                    SB0;
                    VMCNT0;
                }
                LGKM0;
                __builtin_amdgcn_s_barrier();
                SB0;
            }
        }
        // epilogue (transposed D): head-major bf16 Vout
#pragma unroll
        for (int ti = 0; ti < 4; ++ti) {
            int m = m0 + wm * 64 + ti * 16 + lr;
            if (m >= M) continue;
            int b = m >= LV ? 1 : 0;
            int lv = m - (b ? LV : 0);
#pragma unroll
            for (int tj = 0; tj < 4; ++tj) {
                int nb = n0 + wn * 64 + tj * 16 + lq * 4;
                float4 bv = *(const float4*)(b_value + nb);
                int h = nb >> 5, dh = nb & 31;
                unsigned short* dst = Vout + ((size_t)(b * 8 + h) * LV + lv) * 32 + dh;
                *(uint2*)dst = make_uint2(pack2(acc[ti][tj][0] + bv.x, acc[ti][tj][1] + bv.y),
                                          pack2(acc[ti][tj][2] + bv.z, acc[ti][tj][3] + bv.w));
            }
        }
    } else {
        // ---------------- K2: fp32 logits (round-11 gemm_nt_bias) -----------
        const int id = f / 3;
        const int m0 = (id & 127) * 64, n0 = (id >> 7) * 64;
        const int K = 256, N = 256, M = MQ;
        float* As2 = (float*)smem;             // [16][68]
        float* Bs2 = (float*)smem + 16 * 68;   // [16][68]
        int tcol = tid & 15, trow = tid >> 4;
        int lr = tid >> 2, lc = (tid & 3) << 2;
        float acc[4][4] = {};
        for (int k0 = 0; k0 < K; k0 += 16) {
            int arow = m0 + lr; if (arow > M - 1) arow = M - 1;
            float4 av = *(const float4*)(query + (size_t)arow * K + k0 + lc);
            float4 wv = *(const float4*)(Wab + (size_t)(n0 + lr) * K + k0 + lc);
            __syncthreads();
            As2[(lc + 0) * 68 + lr] = av.x; As2[(lc + 1) * 68 + lr] = av.y;
            As2[(lc + 2) * 68 + lr] = av.z; As2[(lc + 3) * 68 + lr] = av.w;
            Bs2[(lc + 0) * 68 + lr] = wv.x; Bs2[(lc + 1) * 68 + lr] = wv.y;
            Bs2[(lc + 2) * 68 + lr] = wv.z; Bs2[(lc + 3) * 68 + lr] = wv.w;
            __syncthreads();
#pragma unroll
            for (int k = 0; k < 16; ++k) {
                float4 a4 = *(const float4*)&As2[k * 68 + (trow << 2)];
                float4 b4 = *(const float4*)&Bs2[k * 68 + (tcol << 2)];
                float a[4] = {a4.x, a4.y, a4.z, a4.w};
                float bb[4] = {b4.x, b4.y, b4.z, b4.w};
#pragma unroll
                for (int i = 0; i < 4; i++)
#pragma unroll
                    for (int j = 0; j < 4; j++) acc[i][j] += a[i] * bb[j];
            }
        }
#pragma unroll
        for (int i = 0; i < 4; i++) {
            int m = m0 + trow * 4 + i;
            if (m >= M) continue;
#pragma unroll
            for (int j = 0; j < 4; j++) {
                int n = n0 + tcol * 4 + j;
                logits[(size_t)m * N + n] = acc[i][j] + bab[n];
            }
        }
    }
}

// ---------------- K4: bf16 MFMA GEMM (round-11, AFP32=0, BM=64) ----------------
__global__ __launch_bounds__(256) void gemm_out(
    const unsigned short* __restrict__ Ab,
    const unsigned short* __restrict__ Bw,
    const float* __restrict__ bias,
    float* __restrict__ C, int M)
{
    constexpr int BM = 64;
    constexpr int NI = BM / 32, TI = BM / 32;
    __shared__ unsigned short As[2][BM * 64];
    __shared__ unsigned short Bs[2][128 * 64];
    const int tid = threadIdx.x;
    const int wv = tid >> 6, lane = tid & 63;
    const int lr = lane & 15, lq = lane >> 4;
    const int m0 = blockIdx.x * BM, n0 = blockIdx.y * 128;
    const int wm = wv & 1, wn = wv >> 1;
    const int srow = tid >> 3;
    const int colg = tid & 7;
    const int colgSw = colg ^ (srow & 7);

    floatx4 acc[TI][4];
#pragma unroll
    for (int i = 0; i < TI; ++i)
#pragma unroll
        for (int j = 0; j < 4; ++j) acc[i][j] = (floatx4){0.f, 0.f, 0.f, 0.f};

    auto compute = [&](const unsigned short* Acur, const unsigned short* Bcur) {
#pragma unroll
        for (int kb = 0; kb < 2; ++kb) {
            shortx8 af[TI], bfr[4];
#pragma unroll
            for (int t = 0; t < TI; ++t) {
                int arow = wm * (BM / 2) + t * 16 + lr;
                af[t] = *(const shortx8*)&Acur[arow * 64 + (((kb * 4 + lq) ^ (arow & 7)) * 8)];
            }
#pragma unroll
            for (int t = 0; t < 4; ++t) {
                int brow = wn * 64 + t * 16 + lr;
                bfr[t] = *(const shortx8*)&Bcur[brow * 64 + (((kb * 4 + lq) ^ (brow & 7)) * 8)];
            }
#pragma unroll
            for (int ti = 0; ti < TI; ++ti)
#pragma unroll
                for (int tj = 0; tj < 4; ++tj)
                    acc[ti][tj] = __builtin_amdgcn_mfma_f32_16x16x32_bf16(bfr[tj], af[ti], acc[ti][tj], 0, 0, 0);
        }
    };

#pragma unroll
    for (int i = 0; i < NI; ++i) {
        int ra = m0 + i * 32 + srow; ra = ra < M ? ra : M - 1;
        async16(Ab + (size_t)ra * 256 + colgSw * 8, (char*)As[0] + i * 4096 + wv * 1024);
    }
#pragma unroll
    for (int i = 0; i < 4; ++i) {
        int rb = n0 + i * 32 + srow;
        async16(Bw + (size_t)rb * 256 + colgSw * 8, (char*)Bs[0] + i * 4096 + wv * 1024);
    }
    __syncthreads();
    int cur = 0;
    for (int kc = 0; kc < 4; ++kc) {
        const int nk = (kc + 1) * 64;
        if (kc < 3) {
#pragma unroll
            for (int i = 0; i < NI; ++i) {
                int ra = m0 + i * 32 + srow; ra = ra < M ? ra : M - 1;
                async16(Ab + (size_t)ra * 256 + nk + colgSw * 8,
                        (char*)As[cur ^ 1] + i * 4096 + wv * 1024);
            }
#pragma unroll
            for (int i = 0; i < 4; ++i) {
                int rb = n0 + i * 32 + srow;
                async16(Bw + (size_t)rb * 256 + nk + colgSw * 8,
                        (char*)Bs[cur ^ 1] + i * 4096 + wv * 1024);
            }
        }
        compute(As[cur], Bs[cur]);
        __syncthreads();
        cur ^= 1;
    }
#pragma unroll
    for (int ti = 0; ti < TI; ++ti) {
        int m = m0 + wm * (BM / 2) + ti * 16 + lr;
        if (m >= M) continue;
        float* Crow = C + (size_t)m * 256;
#pragma unroll
        for (int tj = 0; tj < 4; ++tj) {
            int nb = n0 + wn * 64 + tj * 16 + lq * 4;
            float4 bv = *(const float4*)(bias + nb);
            float4 o = make_float4(acc[ti][tj][0] + bv.x, acc[ti][tj][1] + bv.y,
                                   acc[ti][tj][2] + bv.z, acc[ti][tj][3] + bv.w);
            *(float4*)(Crow + nb) = o;
        }
    }
}

// ---------------- K3: XCD-temporal fused decode + bilinear gather ----------------
__global__ __launch_bounds__(256) void decode_sample_kernel(
    const unsigned short* __restrict__ v,   // bf16 [b*8+h][LV][32]
    const float* __restrict__ logits,       // MQ x 256 (240 real)
    const float* __restrict__ ref_windows,  // MQ x 7
    float* __restrict__ attn_out,           // MQ x 200
    unsigned short* __restrict__ ohbf,      // MQ x 256 bf16
    const int* __restrict__ Hf_p, const int* __restrict__ Wf_p, int LV, int LQ)
{
    __shared__ float lg[8][32];
    __shared__ float rw[8][7];
    __shared__ float prm[8][6];
    __shared__ float mxinv[8][2];
    __shared__ uint4 pk[8][25][2];

    const int lin = blockIdx.y * 16 + blockIdx.x;
    const int nc = gridDim.y;               // LQ/8
    const int seq = lin >> 3;
    const int c = seq % nc;
    const int s = (lin & 7) + ((seq / nc) << 3);
    const int b = s >> 3, h = s & 7;
    const int tid = threadIdx.x;
    const int Hf = *Hf_p, Wf = *Wf_p;
    const size_t mbase = (size_t)b * LQ + c * 8;

    if (tid < 240) {
        int qq = tid / 30, j = tid - qq * 30;
        int col = (j < 25) ? h * 25 + j : 200 + h * 5 + (j - 25);
        lg[qq][j] = logits[(mbase + qq) * 256 + col];
    }
    if (tid < 56) {
        int qq = tid / 7, k = tid - qq * 7;
        rw[qq][k] = ref_windows[(mbase + qq) * 7 + k];
    }
    __syncthreads();

    if (tid < 8) {
        int qq = tid;
        float mx = -1e30f;
#pragma unroll
        for (int p = 0; p < 25; p++) mx = fmaxf(mx, lg[qq][p]);
        float ssum = 0.f;
#pragma unroll
        for (int p = 0; p < 25; p++) ssum += expf(lg[qq][p] - mx);
        mxinv[qq][0] = mx; mxinv[qq][1] = 1.f / ssum;
        float cx = rw[qq][0] + lg[qq][25] * 0.125f * rw[qq][3];
        float cy = rw[qq][1] + lg[qq][26] * 0.125f * rw[qq][4];
        float bw = rw[qq][3] + lg[qq][27] * 0.125f * rw[qq][3];
        float bh = rw[qq][4] + lg[qq][28] * 0.125f * rw[qq][4];
        float ang = (rw[qq][6] + lg[qq][29] * 0.0625f) * 6.283185307179586f;
        prm[qq][0] = cx; prm[qq][1] = cy;
        prm[qq][2] = fmaxf(bw, 0.f); prm[qq][3] = fmaxf(bh, 0.f);
        prm[qq][4] = cosf(ang); prm[qq][5] = sinf(ang);
    }
    __syncthreads();

    if (tid < 200) {
        int qq = tid / 25, p = tid - qq * 25;
        float a = expf(lg[qq][p] - mxinv[qq][0]) * mxinv[qq][1];
        attn_out[(mbase + qq) * 200 + h * 25 + p] = a;
        int pi = p / 5, pj = p - pi * 5;
        float g0 = (float)(pj - 2) * 0.2f * prm[qq][2];
        float g1 = (float)(pi - 2) * 0.2f * prm[qq][3];
        float ca = prm[qq][4], sa = prm[qq][5];
        float gx = (prm[qq][0] + g0 * ca - g1 * sa) * (float)Wf - 0.5f;
        float gy = (prm[qq][1] + g0 * sa + g1 * ca) * (float)Hf - 0.5f;
        float x0f = floorf(gx), y0f = floorf(gy);
        int x0 = (int)x0f, y0 = (int)y0f;
        float wx1 = gx - x0f, wy1 = gy - y0f;
        float wx0 = 1.f - wx1, wy0 = 1.f - wy1;
        int y1 = y0 + 1;
        int bx; float wl, wr;
        if (x0 >= 0 && x0 <= Wf - 2)      { bx = x0;     wl = wx0; wr = wx1; }
        else if (x0 == -1)                { bx = 0;      wl = wx1; wr = 0.f; }
        else if (x0 == Wf - 1)            { bx = Wf - 2; wl = 0.f; wr = wx0; }
        else                              { bx = 0;      wl = 0.f; wr = 0.f; }
        float wy0v = (y0 >= 0 && y0 < Hf) ? wy0 : 0.f;
        float wy1v = (y1 >= 0 && y1 < Hf) ? wy1 : 0.f;
        int cy0 = min(max(y0, 0), Hf - 1), cy1 = min(max(y1, 0), Hf - 1);
        unsigned off0 = (unsigned)(cy0 * Wf + bx) * 16u;
        unsigned off1 = (unsigned)(cy1 * Wf + bx) * 16u;
        float aw0 = a * wy0v, aw1 = a * wy1v;
        pk[qq][p][0] = make_uint4(__float_as_uint(aw0 * wl), __float_as_uint(aw1 * wl), off0, off1);
        pk[qq][p][1] = make_uint4(__float_as_uint(aw0 * wr), __float_as_uint(aw1 * wr), off0, off1);
    }
    __syncthreads();

    const int qq = tid >> 5, l = tid & 31;
    const unsigned int* vw = (const unsigned int*)(v + (size_t)s * LV * 32);
    const uint4* pkp = &pk[qq][0][l >> 4];
    float e0 = 0.f, o0 = 0.f, e1 = 0.f, o1 = 0.f;
#pragma unroll
    for (int p = 0; p < 25; ++p) {
        uint4 t = pkp[2 * p];
        float w0 = __uint_as_float(t.x), w1 = __uint_as_float(t.y);
        unsigned u0 = vw[t.z + l];
        unsigned u1 = vw[t.w + l];
        e0 += w0 * __uint_as_float(u0 << 16);
        o0 += w0 * __uint_as_float(u0 & 0xffff0000u);
        e1 += w1 * __uint_as_float(u1 << 16);
        o1 += w1 * __uint_as_float(u1 & 0xffff0000u);
    }
    float a0 = e0 + e1, a1 = o0 + o1;
    a0 += __shfl_xor(a0, 16, 32);
    a1 += __shfl_xor(a1, 16, 32);
    if (l < 16)
        ((unsigned int*)ohbf)[(mbase + qq) * 128 + h * 16 + l] = pack2(a0, a1);
}

extern "C" void kernel_launch(void* const* d_in, const int* in_sizes, int n_in,
                              void* d_out, int out_size, void* d_ws, size_t ws_size,
                              hipStream_t stream) {
    const float* query       = (const float*)d_in[0];
    const float* value       = (const float*)d_in[1];
    const float* ref_windows = (const float*)d_in[2];
    const float* W_box       = (const float*)d_in[3];
    const float* b_box       = (const float*)d_in[4];
    const float* W_attn      = (const float*)d_in[5];
    const float* b_attn      = (const float*)d_in[6];
    const float* W_value     = (const float*)d_in[7];
    const float* b_value     = (const float*)d_in[8];
    const float* W_out       = (const float*)d_in[9];
    const float* b_out       = (const float*)d_in[10];
    const int*   Hf          = (const int*)d_in[11];
    const int*   Wf          = (const int*)d_in[12];

    const int M1 = in_sizes[1] / 256;  // B*LV = 70688
    const int MQ = in_sizes[0] / 256;  // B*LQ = 8192
    const int LQ = MQ / 2;
    const int LV = M1 / 2;

    unsigned short* Vout = (unsigned short*)d_ws;                 // M1*256
    unsigned short* ohbf = Vout + (size_t)M1 * 256;               // MQ*256
    unsigned short* wvbf = ohbf + (size_t)MQ * 256;               // 65536
    unsigned short* wobf = wvbf + 65536;                          // 65536
    float* Wab       = (float*)(wobf + 65536);                    // 65536 fp32
    float* bab       = Wab + 65536;                               // 256
    float* logits    = bab + 256;                                 // MQ*256

    float* out0     = (float*)d_out;
    float* attn_out = out0 + (size_t)MQ * 256;

    // K0: weight conversions
    convert_kernel<<<49, 256, 0, stream>>>(W_value, wvbf, W_attn, W_box, Wab,
                                           W_out, wobf, b_attn, b_box, bab);
    // K12: fused value projection (1106 blocks) + logits (512 blocks), 3:1 mix
    fused_proj<<<1618, 256, 0, stream>>>(value, wvbf, b_value, Vout, M1, LV,
                                         query, Wab, bab, logits, MQ);
    // K3: XCD-temporal fused softmax + box decode + gather -> bf16 out_heads
    decode_sample_kernel<<<dim3(16, LQ / 8), 256, 0, stream>>>(
        Vout, logits, ref_windows, attn_out, ohbf, Hf, Wf, LV, LQ);
    // K4: output projection
    dim3 g4(MQ / 64, 2);
    gemm_out<<<g4, 256, 0, stream>>>(ohbf, wobf, b_out, out0, MQ);
}

// Round 8
// 216.368 us; speedup vs baseline: 1.1624x; 1.0590x over previous
//
#include <hip/hip_runtime.h>

// Box3dAttention: B=2, LQ=4096, d=256, heads=8, head_dim=32, 5x5=25 points,
// feature map 188x188 (LV=35344).
//
// Round 16 = round 11 pipeline (best verified 212.4us) with K1 rebuilt as a
// BYTE-MINIMAL persistent kernel. Evidence: r11 K1 moved 248MB through the
// per-CU vector-memory pipe (A fp32 staged 2x + B restaged per block) at
// 9.2 B/cyc/CU ~= the 10 B/cyc/CU pipe ceiling (m13). All scheduling
// rewrites failed because none cut bytes. This one cuts bytes:
//   A fp32 staged ONCE (BN=256, reg-stage+f2bf pack)      72 MB
//   B resident in LDS, staged ONCE per block (async16)     33 MB
//   Vout writes                                            35 MB
//   => ~140MB ~= 23us pipe floor (was 248MB / 44us).
// Structure: 256 blocks (1/CU) x 512 thr; B 128KB swizzled [256][256] bf16;
// A 2x8KB LDS dbuf per 64-row m-iter; grid-stride over 1105 iters (fine
// granularity = no tail quantization); 1 barrier/kc; acc 2x4 = 32 VGPR.
// r15's branch-fused K12 reverted (VGPR=max(paths)=144 -> 9.6% occupancy).
//
// Pipeline:
//  K0 convert    : W_value/W_out -> bf16, [W_attn;W_box] -> fp32 pad, bias pad
//  K1 gemm_vproj : value fp32 @ wvbf^T + b_value -> Vout bf16 head-major
//  K2 gemm_nt    : fp32 VALU logits = query @ [W_attn;W_box]^T + b
//  K3 decode_sample: XCD-temporal remap fused decode+gather
//  K4 gemm_out   : ohbf @ wobf^T + b_out -> out fp32 (round-11 verified)

typedef float floatx4 __attribute__((ext_vector_type(4)));
typedef short shortx8 __attribute__((ext_vector_type(8)));

static __device__ __forceinline__ unsigned short f2bf(float x) {
    unsigned int u = __float_as_uint(x);
    return (unsigned short)((u + 0x7fffu + ((u >> 16) & 1u)) >> 16);
}
static __device__ __forceinline__ unsigned int pack2(float a, float b) {
    return (unsigned int)f2bf(a) | ((unsigned int)f2bf(b) << 16);
}
static __device__ __forceinline__ void async16(const void* g, void* lds) {
    __builtin_amdgcn_global_load_lds(
        (const __attribute__((address_space(1))) unsigned int*)g,
        (__attribute__((address_space(3))) unsigned int*)lds, 16, 0, 0);
}

// ---------------- K0: weight/bias conversions only ----------------
__global__ __launch_bounds__(256) void convert_kernel(
    const float* __restrict__ W_value, unsigned short* __restrict__ wvbf,
    const float* __restrict__ W_attn, const float* __restrict__ W_box,
    float* __restrict__ Wab,
    const float* __restrict__ W_out, unsigned short* __restrict__ wobf,
    const float* __restrict__ b_attn, const float* __restrict__ b_box,
    float* __restrict__ bab)
{
    const int blk = blockIdx.x, tid = threadIdx.x;
    if (blk < 16) {
        int base = blk * 1024 + tid;
#pragma unroll
        for (int k = 0; k < 4; ++k) {
            int j = base + k * 256;
            float4 f = ((const float4*)W_value)[j];
            ((uint2*)wvbf)[j] = make_uint2(pack2(f.x, f.y), pack2(f.z, f.w));
        }
    } else if (blk < 32) {
        int base = (blk - 16) * 1024 + tid;
#pragma unroll
        for (int k = 0; k < 4; ++k) {
            int j = base + k * 256;
            int row = j >> 6, col = (j & 63) * 4;
            float4 f;
            if (row < 200)      f = *(const float4*)(W_attn + (size_t)row * 256 + col);
            else if (row < 240) f = *(const float4*)(W_box + (size_t)(row - 200) * 256 + col);
            else                f = make_float4(0.f, 0.f, 0.f, 0.f);
            ((float4*)Wab)[j] = f;
        }
    } else if (blk < 48) {
        int base = (blk - 32) * 1024 + tid;
#pragma unroll
        for (int k = 0; k < 4; ++k) {
            int j = base + k * 256;
            float4 f = ((const float4*)W_out)[j];
            ((uint2*)wobf)[j] = make_uint2(pack2(f.x, f.y), pack2(f.z, f.w));
        }
    } else {
        bab[tid] = tid < 200 ? b_attn[tid] : (tid < 240 ? b_box[tid - 200] : 0.f);
    }
}

// ---------------- K1: byte-minimal persistent value projection ----------------
// Vout = value(M x 256 fp32) @ wvbf(256x256 bf16)^T + b_value, head-major bf16.
// 512 thr = 8 waves (wm=wv&1 m-half of 32 rows, wn=wv>>1 n-quarter of 64).
// B resident: LDS [256 rows][32 granules], granule g stored at g^(row&7)
//   (row stride 512B == bank-aligned; swizzle makes frag reads ~2-way).
// A: per 64-row m-iter, 4 kc steps; A[kc] = 64x64 bf16 (8KB) double-buffered;
//   each thread reg-loads 2 float4 fp32 (prefetched one phase ahead), packs
//   (f2bf RNE, bitwise-identical), ds_writes 1 swizzled granule.
__global__ __launch_bounds__(512) void gemm_vproj(
    const float* __restrict__ A,
    const unsigned short* __restrict__ Bw,
    const float* __restrict__ bias,
    unsigned short* __restrict__ Vout, int M, int LV)
{
    __shared__ unsigned short Bres[256 * 256];   // 131072 B
    __shared__ unsigned short As[2][64 * 64];    // 2 x 8192 B
    const int tid = threadIdx.x;
    const int wv = tid >> 6, lane = tid & 63;
    const int lr = lane & 15, lq = lane >> 4;
    const int wm = wv & 1, wn = wv >> 1;
    const int rowA = tid >> 3;          // 0..63 (A staging row)
    const int gA = tid & 7;             // A staging granule (source col group)
    const int gAsw = gA ^ (rowA & 7);   // swizzled dest granule

    // ---- B resident stage: 8192 granules via async16, pre-swizzled source ----
#pragma unroll
    for (int j = 0; j < 16; ++j) {
        int G = j * 512 + tid;           // = j*512 + wv*64 + lane
        int row = G >> 5, g = G & 31;
        async16(Bw + (size_t)row * 256 + (g ^ (row & 7)) * 8,
                (char*)Bres + j * 8192 + wv * 1024);   // + lane*16 by HW
    }

    const int niter = (M + 63) / 64;
    const int stride = gridDim.x;

    // ---- prologue: A(it0, kc=0) regs -> pack -> As[0] ----
    int it0 = blockIdx.x;
    float4 pf0, pf1;
    {
        int ra = it0 * 64 + rowA; ra = ra < M ? ra : M - 1;
        const float* ap = A + (size_t)ra * 256 + gA * 8;
        pf0 = *(const float4*)ap; pf1 = *(const float4*)(ap + 4);
        uint4 pv = make_uint4(pack2(pf0.x, pf0.y), pack2(pf0.z, pf0.w),
                              pack2(pf1.x, pf1.y), pack2(pf1.z, pf1.w));
        *(uint4*)((char*)As[0] + rowA * 128 + gAsw * 16) = pv;
    }
    __syncthreads();   // drains B asyncs + A ds_writes

    int buf = 0;
    for (int it = it0; it < niter; it += stride) {
        const int m0 = it * 64;
        floatx4 acc[2][4];
#pragma unroll
        for (int i = 0; i < 2; ++i)
#pragma unroll
            for (int j = 0; j < 4; ++j) acc[i][j] = (floatx4){0.f, 0.f, 0.f, 0.f};

#pragma unroll
        for (int kc = 0; kc < 4; ++kc) {
            // ---- prefetch next A phase (kc+1, or next iter kc=0) ----
            int nit = it, nkc = kc + 1;
            if (nkc == 4) { nkc = 0; nit = it + stride; if (nit >= niter) nit = it; }
            {
                int ra = nit * 64 + rowA; ra = ra < M ? ra : M - 1;
                const float* ap = A + (size_t)ra * 256 + nkc * 64 + gA * 8;
                pf0 = *(const float4*)ap; pf1 = *(const float4*)(ap + 4);
            }
            // ---- compute on As[buf] x Bres[kc panel] ----
#pragma unroll
            for (int kb = 0; kb < 2; ++kb) {
                shortx8 af[2], bfr[4];
#pragma unroll
                for (int t = 0; t < 2; ++t) {
                    int arow = wm * 32 + t * 16 + lr;
                    af[t] = *(const shortx8*)((const char*)As[buf] + arow * 128 +
                                              (((kb * 4 + lq) ^ (arow & 7)) * 16));
                }
#pragma unroll
                for (int t = 0; t < 4; ++t) {
                    int brow = wn * 64 + t * 16 + lr;
                    int gg = kc * 8 + kb * 4 + lq;
                    bfr[t] = *(const shortx8*)((const char*)Bres + brow * 512 +
                                               ((gg ^ (brow & 7)) * 16));
                }
#pragma unroll
                for (int ti = 0; ti < 2; ++ti)
#pragma unroll
                    for (int tj = 0; tj < 4; ++tj)
                        acc[ti][tj] = __builtin_amdgcn_mfma_f32_16x16x32_bf16(bfr[tj], af[ti], acc[ti][tj], 0, 0, 0);
            }
            // ---- pack + write next A phase into As[buf^1] ----
            {
                uint4 pv = make_uint4(pack2(pf0.x, pf0.y), pack2(pf0.z, pf0.w),
                                      pack2(pf1.x, pf1.y), pack2(pf1.z, pf1.w));
                *(uint4*)((char*)As[buf ^ 1] + rowA * 128 + gAsw * 16) = pv;
            }
            __syncthreads();
            buf ^= 1;
        }
        // ---- epilogue: head-major bf16 store (transposed D) ----
#pragma unroll
        for (int ti = 0; ti < 2; ++ti) {
            int m = m0 + wm * 32 + ti * 16 + lr;
            if (m >= M) continue;
            int b = m >= LV ? 1 : 0;
            int lv = m - (b ? LV : 0);
#pragma unroll
            for (int tj = 0; tj < 4; ++tj) {
                int nb = wn * 64 + tj * 16 + lq * 4;
                float4 bv = *(const float4*)(bias + nb);
                int h = nb >> 5, dh = nb & 31;
                unsigned short* dst = Vout + ((size_t)(b * 8 + h) * LV + lv) * 32 + dh;
                *(uint2*)dst = make_uint2(pack2(acc[ti][tj][0] + bv.x, acc[ti][tj][1] + bv.y),
                                          pack2(acc[ti][tj][2] + bv.z, acc[ti][tj][3] + bv.w));
            }
        }
    }
}

// ---------------- K2: fp32 tiled GEMM (logits, accuracy-critical) ----------------
__global__ __launch_bounds__(256) void gemm_nt_bias(
    const float* __restrict__ A, const float* __restrict__ W,
    const float* __restrict__ bias, float* __restrict__ C, int M)
{
    const int K = 256, N = 256;
    __shared__ float As[16][68];
    __shared__ float Bs[16][68];
    int tid = threadIdx.x;
    int tcol = tid & 15, trow = tid >> 4;
    int m0 = blockIdx.x * 64, n0 = blockIdx.y * 64;
    int lr = tid >> 2, lc = (tid & 3) << 2;
    float acc[4][4] = {};
    for (int k0 = 0; k0 < K; k0 += 16) {
        int arow = m0 + lr; if (arow > M - 1) arow = M - 1;
        float4 av = *(const float4*)(A + (size_t)arow * K + k0 + lc);
        float4 wv = *(const float4*)(W + (size_t)(n0 + lr) * K + k0 + lc);
        __syncthreads();
        As[lc + 0][lr] = av.x; As[lc + 1][lr] = av.y; As[lc + 2][lr] = av.z; As[lc + 3][lr] = av.w;
        Bs[lc + 0][lr] = wv.x; Bs[lc + 1][lr] = wv.y; Bs[lc + 2][lr] = wv.z; Bs[lc + 3][lr] = wv.w;
        __syncthreads();
#pragma unroll
        for (int k = 0; k < 16; ++k) {
            float4 a4 = *(const float4*)&As[k][trow << 2];
            float4 b4 = *(const float4*)&Bs[k][tcol << 2];
            float a[4] = {a4.x, a4.y, a4.z, a4.w};
            float bb[4] = {b4.x, b4.y, b4.z, b4.w};
#pragma unroll
            for (int i = 0; i < 4; i++)
#pragma unroll
                for (int j = 0; j < 4; j++) acc[i][j] += a[i] * bb[j];
        }
    }
#pragma unroll
    for (int i = 0; i < 4; i++) {
        int m = m0 + trow * 4 + i;
        if (m >= M) continue;
#pragma unroll
        for (int j = 0; j < 4; j++) {
            int n = n0 + tcol * 4 + j;
            C[(size_t)m * N + n] = acc[i][j] + bias[n];
        }
    }
}

// ---------------- K3: XCD-temporal fused decode + bilinear gather ----------------
__global__ __launch_bounds__(256) void decode_sample_kernel(
    const unsigned short* __restrict__ v,   // bf16 [b*8+h][LV][32]
    const float* __restrict__ logits,       // MQ x 256 (240 real)
    const float* __restrict__ ref_windows,  // MQ x 7
    float* __restrict__ attn_out,           // MQ x 200
    unsigned short* __restrict__ ohbf,      // MQ x 256 bf16
    const int* __restrict__ Hf_p, const int* __restrict__ Wf_p, int LV, int LQ)
{
    __shared__ float lg[8][32];
    __shared__ float rw[8][7];
    __shared__ float prm[8][6];
    __shared__ float mxinv[8][2];
    __shared__ uint4 pk[8][25][2];

    const int lin = blockIdx.y * 16 + blockIdx.x;
    const int nc = gridDim.y;               // LQ/8
    const int seq = lin >> 3;
    const int c = seq % nc;
    const int s = (lin & 7) + ((seq / nc) << 3);
    const int b = s >> 3, h = s & 7;
    const int tid = threadIdx.x;
    const int Hf = *Hf_p, Wf = *Wf_p;
    const size_t mbase = (size_t)b * LQ + c * 8;

    if (tid < 240) {
        int qq = tid / 30, j = tid - qq * 30;
        int col = (j < 25) ? h * 25 + j : 200 + h * 5 + (j - 25);
        lg[qq][j] = logits[(mbase + qq) * 256 + col];
    }
    if (tid < 56) {
        int qq = tid / 7, k = tid - qq * 7;
        rw[qq][k] = ref_windows[(mbase + qq) * 7 + k];
    }
    __syncthreads();

    if (tid < 8) {
        int qq = tid;
        float mx = -1e30f;
#pragma unroll
        for (int p = 0; p < 25; p++) mx = fmaxf(mx, lg[qq][p]);
        float ssum = 0.f;
#pragma unroll
        for (int p = 0; p < 25; p++) ssum += expf(lg[qq][p] - mx);
        mxinv[qq][0] = mx; mxinv[qq][1] = 1.f / ssum;
        float cx = rw[qq][0] + lg[qq][25] * 0.125f * rw[qq][3];
        float cy = rw[qq][1] + lg[qq][26] * 0.125f * rw[qq][4];
        float bw = rw[qq][3] + lg[qq][27] * 0.125f * rw[qq][3];
        float bh = rw[qq][4] + lg[qq][28] * 0.125f * rw[qq][4];
        float ang = (rw[qq][6] + lg[qq][29] * 0.0625f) * 6.283185307179586f;
        prm[qq][0] = cx; prm[qq][1] = cy;
        prm[qq][2] = fmaxf(bw, 0.f); prm[qq][3] = fmaxf(bh, 0.f);
        prm[qq][4] = cosf(ang); prm[qq][5] = sinf(ang);
    }
    __syncthreads();

    if (tid < 200) {
        int qq = tid / 25, p = tid - qq * 25;
        float a = expf(lg[qq][p] - mxinv[qq][0]) * mxinv[qq][1];
        attn_out[(mbase + qq) * 200 + h * 25 + p] = a;
        int pi = p / 5, pj = p - pi * 5;
        float g0 = (float)(pj - 2) * 0.2f * prm[qq][2];
        float g1 = (float)(pi - 2) * 0.2f * prm[qq][3];
        float ca = prm[qq][4], sa = prm[qq][5];
        float gx = (prm[qq][0] + g0 * ca - g1 * sa) * (float)Wf - 0.5f;
        float gy = (prm[qq][1] + g0 * sa + g1 * ca) * (float)Hf - 0.5f;
        float x0f = floorf(gx), y0f = floorf(gy);
        int x0 = (int)x0f, y0 = (int)y0f;
        float wx1 = gx - x0f, wy1 = gy - y0f;
        float wx0 = 1.f - wx1, wy0 = 1.f - wy1;
        int y1 = y0 + 1;
        int bx; float wl, wr;
        if (x0 >= 0 && x0 <= Wf - 2)      { bx = x0;     wl = wx0; wr = wx1; }
        else if (x0 == -1)                { bx = 0;      wl = wx1; wr = 0.f; }
        else if (x0 == Wf - 1)            { bx = Wf - 2; wl = 0.f; wr = wx0; }
        else                              { bx = 0;      wl = 0.f; wr = 0.f; }
        float wy0v = (y0 >= 0 && y0 < Hf) ? wy0 : 0.f;
        float wy1v = (y1 >= 0 && y1 < Hf) ? wy1 : 0.f;
        int cy0 = min(max(y0, 0), Hf - 1), cy1 = min(max(y1, 0), Hf - 1);
        unsigned off0 = (unsigned)(cy0 * Wf + bx) * 16u;
        unsigned off1 = (unsigned)(cy1 * Wf + bx) * 16u;
        float aw0 = a * wy0v, aw1 = a * wy1v;
        pk[qq][p][0] = make_uint4(__float_as_uint(aw0 * wl), __float_as_uint(aw1 * wl), off0, off1);
        pk[qq][p][1] = make_uint4(__float_as_uint(aw0 * wr), __float_as_uint(aw1 * wr), off0, off1);
    }
    __syncthreads();

    const int qq = tid >> 5, l = tid & 31;
    const unsigned int* vw = (const unsigned int*)(v + (size_t)s * LV * 32);
    const uint4* pkp = &pk[qq][0][l >> 4];
    float e0 = 0.f, o0 = 0.f, e1 = 0.f, o1 = 0.f;
#pragma unroll
    for (int p = 0; p < 25; ++p) {
        uint4 t = pkp[2 * p];
        float w0 = __uint_as_float(t.x), w1 = __uint_as_float(t.y);
        unsigned u0 = vw[t.z + l];
        unsigned u1 = vw[t.w + l];
        e0 += w0 * __uint_as_float(u0 << 16);
        o0 += w0 * __uint_as_float(u0 & 0xffff0000u);
        e1 += w1 * __uint_as_float(u1 << 16);
        o1 += w1 * __uint_as_float(u1 & 0xffff0000u);
    }
    float a0 = e0 + e1, a1 = o0 + o1;
    a0 += __shfl_xor(a0, 16, 32);
    a1 += __shfl_xor(a1, 16, 32);
    if (l < 16)
        ((unsigned int*)ohbf)[(mbase + qq) * 128 + h * 16 + l] = pack2(a0, a1);
}

// ---------------- K4: bf16 MFMA GEMM (round-11 verified, BM=64) ----------------
__global__ __launch_bounds__(256) void gemm_out(
    const unsigned short* __restrict__ Ab,
    const unsigned short* __restrict__ Bw,
    const float* __restrict__ bias,
    float* __restrict__ C, int M)
{
    constexpr int BM = 64;
    constexpr int NI = BM / 32, TI = BM / 32;
    __shared__ unsigned short As[2][BM * 64];
    __shared__ unsigned short Bs[2][128 * 64];
    const int tid = threadIdx.x;
    const int wv = tid >> 6, lane = tid & 63;
    const int lr = lane & 15, lq = lane >> 4;
    const int m0 = blockIdx.x * BM, n0 = blockIdx.y * 128;
    const int wm = wv & 1, wn = wv >> 1;
    const int srow = tid >> 3;
    const int colg = tid & 7;
    const int colgSw = colg ^ (srow & 7);

    floatx4 acc[TI][4];
#pragma unroll
    for (int i = 0; i < TI; ++i)
#pragma unroll
        for (int j = 0; j < 4; ++j) acc[i][j] = (floatx4){0.f, 0.f, 0.f, 0.f};

    auto compute = [&](const unsigned short* Acur, const unsigned short* Bcur) {
#pragma unroll
        for (int kb = 0; kb < 2; ++kb) {
            shortx8 af[TI], bfr[4];
#pragma unroll
            for (int t = 0; t < TI; ++t) {
                int arow = wm * (BM / 2) + t * 16 + lr;
                af[t] = *(const shortx8*)&Acur[arow * 64 + (((kb * 4 + lq) ^ (arow & 7)) * 8)];
            }
#pragma unroll
            for (int t = 0; t < 4; ++t) {
                int brow = wn * 64 + t * 16 + lr;
                bfr[t] = *(const shortx8*)&Bcur[brow * 64 + (((kb * 4 + lq) ^ (brow & 7)) * 8)];
            }
#pragma unroll
            for (int ti = 0; ti < TI; ++ti)
#pragma unroll
                for (int tj = 0; tj < 4; ++tj)
                    acc[ti][tj] = __builtin_amdgcn_mfma_f32_16x16x32_bf16(bfr[tj], af[ti], acc[ti][tj], 0, 0, 0);
        }
    };

#pragma unroll
    for (int i = 0; i < NI; ++i) {
        int ra = m0 + i * 32 + srow; ra = ra < M ? ra : M - 1;
        async16(Ab + (size_t)ra * 256 + colgSw * 8, (char*)As[0] + i * 4096 + wv * 1024);
    }
#pragma unroll
    for (int i = 0; i < 4; ++i) {
        int rb = n0 + i * 32 + srow;
        async16(Bw + (size_t)rb * 256 + colgSw * 8, (char*)Bs[0] + i * 4096 + wv * 1024);
    }
    __syncthreads();
    int cur = 0;
    for (int kc = 0; kc < 4; ++kc) {
        const int nk = (kc + 1) * 64;
        if (kc < 3) {
#pragma unroll
            for (int i = 0; i < NI; ++i) {
                int ra = m0 + i * 32 + srow; ra = ra < M ? ra : M - 1;
                async16(Ab + (size_t)ra * 256 + nk + colgSw * 8,
                        (char*)As[cur ^ 1] + i * 4096 + wv * 1024);
            }
#pragma unroll
            for (int i = 0; i < 4; ++i) {
                int rb = n0 + i * 32 + srow;
                async16(Bw + (size_t)rb * 256 + nk + colgSw * 8,
                        (char*)Bs[cur ^ 1] + i * 4096 + wv * 1024);
            }
        }
        compute(As[cur], Bs[cur]);
        __syncthreads();
        cur ^= 1;
    }
#pragma unroll
    for (int ti = 0; ti < TI; ++ti) {
        int m = m0 + wm * (BM / 2) + ti * 16 + lr;
        if (m >= M) continue;
        float* Crow = C + (size_t)m * 256;
#pragma unroll
        for (int tj = 0; tj < 4; ++tj) {
            int nb = n0 + wn * 64 + tj * 16 + lq * 4;
            float4 bv = *(const float4*)(bias + nb);
            float4 o = make_float4(acc[ti][tj][0] + bv.x, acc[ti][tj][1] + bv.y,
                                   acc[ti][tj][2] + bv.z, acc[ti][tj][3] + bv.w);
            *(float4*)(Crow + nb) = o;
        }
    }
}

extern "C" void kernel_launch(void* const* d_in, const int* in_sizes, int n_in,
                              void* d_out, int out_size, void* d_ws, size_t ws_size,
                              hipStream_t stream) {
    const float* query       = (const float*)d_in[0];
    const float* value       = (const float*)d_in[1];
    const float* ref_windows = (const float*)d_in[2];
    const float* W_box       = (const float*)d_in[3];
    const float* b_box       = (const float*)d_in[4];
    const float* W_attn      = (const float*)d_in[5];
    const float* b_attn      = (const float*)d_in[6];
    const float* W_value     = (const float*)d_in[7];
    const float* b_value     = (const float*)d_in[8];
    const float* W_out       = (const float*)d_in[9];
    const float* b_out       = (const float*)d_in[10];
    const int*   Hf          = (const int*)d_in[11];
    const int*   Wf          = (const int*)d_in[12];

    const int M1 = in_sizes[1] / 256;  // B*LV = 70688
    const int MQ = in_sizes[0] / 256;  // B*LQ = 8192
    const int LQ = MQ / 2;
    const int LV = M1 / 2;

    unsigned short* Vout = (unsigned short*)d_ws;                 // M1*256
    unsigned short* ohbf = Vout + (size_t)M1 * 256;               // MQ*256
    unsigned short* wvbf = ohbf + (size_t)MQ * 256;               // 65536
    unsigned short* wobf = wvbf + 65536;                          // 65536
    float* Wab       = (float*)(wobf + 65536);                    // 65536 fp32
    float* bab       = Wab + 65536;                               // 256
    float* logits    = bab + 256;                                 // MQ*256

    float* out0     = (float*)d_out;
    float* attn_out = out0 + (size_t)MQ * 256;

    // K0: weight conversions
    convert_kernel<<<49, 256, 0, stream>>>(W_value, wvbf, W_attn, W_box, Wab,
                                           W_out, wobf, b_attn, b_box, bab);
    // K1: byte-minimal persistent value projection (256 blocks = 1/CU)
    gemm_vproj<<<256, 512, 0, stream>>>(value, wvbf, b_value, Vout, M1, LV);
    // K2: logits fp32 (accuracy-critical box path)
    dim3 g2(MQ / 64, 4);
    gemm_nt_bias<<<g2, 256, 0, stream>>>(query, Wab, bab, logits, MQ);
    // K3: XCD-temporal fused softmax + box decode + gather -> bf16 out_heads
    decode_sample_kernel<<<dim3(16, LQ / 8), 256, 0, stream>>>(
        Vout, logits, ref_windows, attn_out, ohbf, Hf, Wf, LV, LQ);
    // K4: output projection (round-11 verified LDS dbuf kernel)
    dim3 g4(MQ / 64, 2);
    gemm_out<<<g4, 256, 0, stream>>>(ohbf, wobf, b_out, out0, MQ);
}